// Round 10
// baseline (961.197 us; speedup 1.0000x reference)
//
#include <hip/hip_runtime.h>

// ============================================================================
// TemporalPointNet (PointNet++ style) forward on MI355X.
// B=2, T=4 -> BT=8 "batches", N=4096 points, 4 coords (xyz + t).
// SA1: npoint=512, r=0.2, K=32, C_in=4,  MLP 64,64,128
// SA2: npoint=128, r=0.4, K=64, C_in=131, MLP 128,128,256
// SA3: group_all,          K=128, C_in=259, MLP 256,512,1024
// Output: (2,4,1024) f32 = 8192 floats.
//
// R10: (1) FPS argmax via single lexicographic 64-bit DPP chain (was two
// dependent 32-bit chains). (2) memset shrunk to metadata region only (A/XG
// verified fully-written-before-read at every use). (3) query_ball+group
// fused for SA1 (finding lane writes its grouped row directly).
// GEMM structure (split-bf16 triple MFMA + stats epilogue) unchanged from R9.
// ============================================================================

typedef short s16x8 __attribute__((ext_vector_type(8)));
typedef float f32x4 __attribute__((ext_vector_type(4)));

__device__ __forceinline__ unsigned short f2bf_rne(float f) {
    unsigned u = __float_as_uint(f);
    u += 0x7FFFu + ((u >> 16) & 1u);
    return (unsigned short)(u >> 16);
}
// split f32 -> (hi, lo) bf16 pair: hi = rne(v), lo = rne(v - hi)
__device__ __forceinline__ void f2bf_split(float v, unsigned short& hi,
                                           unsigned short& lo) {
    unsigned u = __float_as_uint(v);
    unsigned r = u + 0x7FFFu + ((u >> 16) & 1u);
    hi = (unsigned short)(r >> 16);
    float vh = __uint_as_float(r & 0xFFFF0000u);
    lo = f2bf_rne(v - vh);
}

__device__ __forceinline__ unsigned long long umax64(unsigned long long a,
                                                     unsigned long long b) {
    return a > b ? a : b;
}

// Wave64 lexicographic max-reduce of (hi, lo) pairs via DPP (LLVM
// atomic-optimizer lane routing). Identity (0,0) is safe: hi = dist bits >= 0.
// Result valid in lane 63.
__device__ __forceinline__ void wred_kmax63(unsigned& hi, unsigned& lo) {
#define KSTEP(ctrl, rmask)                                                     \
    {                                                                          \
        unsigned th = (unsigned)__builtin_amdgcn_update_dpp(0, (int)hi, ctrl,  \
                                                            rmask, 0xf, true); \
        unsigned tl = (unsigned)__builtin_amdgcn_update_dpp(0, (int)lo, ctrl,  \
                                                            rmask, 0xf, true); \
        if (th > hi || (th == hi && tl > lo)) { hi = th; lo = tl; }            \
    }
    KSTEP(0x111, 0xf)   // row_shr:1
    KSTEP(0x112, 0xf)   // row_shr:2
    KSTEP(0x114, 0xf)   // row_shr:4
    KSTEP(0x118, 0xf)   // row_shr:8
    KSTEP(0x142, 0xa)   // row_bcast:15
    KSTEP(0x143, 0xc)   // row_bcast:31
#undef KSTEP
}

// Wave argmax of (dist, min-index). dist >= 0 -> float bit order == value
// order; nInv = ~n -> lexicographic max picks max dist then lowest index.
// Exact first-occurrence argmax.
__device__ __forceinline__ void wave_argmax(unsigned dbits, unsigned nInv,
                                            unsigned& vmax, unsigned& iInv) {
    unsigned h = dbits, l = nInv;
    wred_kmax63(h, l);
    vmax = (unsigned)__builtin_amdgcn_readlane((int)h, 63);
    iInv = (unsigned)__builtin_amdgcn_readlane((int)l, 63);
}

// ---------------- FPS (multi-wave): one block (NT thr) per batch ------------
// R7 structure (measured best): scoord table + per-wave u64 keys; combine =
// NW u64 reads + one broadcast b128. jnp semantics: dist init 1e10,
// d = ((dx^2+dy^2)+dz^2) rn ops (no fma), argmax = FIRST occurrence of max.
template<int NT, int ITEMS, int STRIDE>
__global__ __launch_bounds__(NT) void fps_block(
    const float* __restrict__ pts, int npoint,
    int* __restrict__ outIdx, float* __restrict__ outXyz)
{
    constexpr int N = NT * ITEMS;
    constexpr int NW = NT / 64;
    __shared__ float4 scoord[N];
    __shared__ unsigned long long wkey[2][NW];

    const int b = blockIdx.x;
    const int tid = threadIdx.x;
    const int wid = tid >> 6;
    const int lane = tid & 63;
    const float* P = pts + (size_t)b * N * STRIDE;

    float px[ITEMS], py[ITEMS], pz[ITEMS], dloc[ITEMS];
#pragma unroll
    for (int w = 0; w < ITEMS; ++w) {
        int n = tid + w * NT;
        float x, y, z;
        if (STRIDE == 4) {
            float4 v = *(const float4*)(P + (size_t)n * 4);
            x = v.x; y = v.y; z = v.z;
        } else {
            x = P[(size_t)n * STRIDE + 0];
            y = P[(size_t)n * STRIDE + 1];
            z = P[(size_t)n * STRIDE + 2];
        }
        px[w] = x; py[w] = y; pz[w] = z;
        scoord[n] = make_float4(x, y, z, 0.f);
        dloc[w] = 1e10f;
    }
    __syncthreads();
    float4 c0 = scoord[0];
    float cx = c0.x, cy = c0.y, cz = c0.z;
    int far = 0;

    for (int i = 0; i < npoint; ++i) {
        if (tid == 0) {
            outIdx[(size_t)b * npoint + i] = far;
            outXyz[((size_t)b * npoint + i) * 3 + 0] = cx;
            outXyz[((size_t)b * npoint + i) * 3 + 1] = cy;
            outXyz[((size_t)b * npoint + i) * 3 + 2] = cz;
        }
        float bestV = -1.0f;
        int bestW = 0;
#pragma unroll
        for (int w = 0; w < ITEMS; ++w) {
            float dx = __fsub_rn(px[w], cx);
            float dy = __fsub_rn(py[w], cy);
            float dz = __fsub_rn(pz[w], cz);
            float d = __fadd_rn(__fadd_rn(__fmul_rn(dx, dx), __fmul_rn(dy, dy)),
                                __fmul_rn(dz, dz));
            float dd = fminf(dloc[w], d);
            dloc[w] = dd;
            if (dd > bestV) { bestV = dd; bestW = w; }  // strict > : lowest w kept
        }
        int bestN = tid + bestW * NT;   // n grows with w -> min n on tie
        unsigned vmax, iInv;
        wave_argmax(__float_as_uint(bestV), 0xFFFFFFFFu ^ (unsigned)bestN,
                    vmax, iInv);
        const int par = i & 1;
        if (lane == 0)
            wkey[par][wid] = ((unsigned long long)vmax << 32) | iInv;
        __syncthreads();   // single barrier per iteration (parity dbuf)
        unsigned long long kb = wkey[par][0];
#pragma unroll
        for (int w2 = 1; w2 < NW; ++w2) kb = umax64(kb, wkey[par][w2]);
        far = (int)(0xFFFFFFFFu ^ (unsigned)kb);
        float4 cc = scoord[far];   // broadcast, conflict-free
        cx = cc.x; cy = cc.y; cz = cc.z;
    }
}

// ---------------- FPS (single wave): no barriers at all ---------------------
template<int ITEMS, int STRIDE>
__global__ __launch_bounds__(64) void fps_wave(
    const float* __restrict__ pts, int npoint,
    int* __restrict__ outIdx, float* __restrict__ outXyz)
{
    constexpr int N = 64 * ITEMS;
    __shared__ float4 scoord[N];

    const int b = blockIdx.x;
    const int tid = threadIdx.x;
    const float* P = pts + (size_t)b * N * STRIDE;

    float px[ITEMS], py[ITEMS], pz[ITEMS], dloc[ITEMS];
#pragma unroll
    for (int w = 0; w < ITEMS; ++w) {
        int n = tid + w * 64;
        float x = P[(size_t)n * STRIDE + 0];
        float y = P[(size_t)n * STRIDE + 1];
        float z = P[(size_t)n * STRIDE + 2];
        px[w] = x; py[w] = y; pz[w] = z;
        scoord[n] = make_float4(x, y, z, 0.f);
        dloc[w] = 1e10f;
    }
    __syncthreads();
    float4 c0 = scoord[0];
    float cx = c0.x, cy = c0.y, cz = c0.z;
    int far = 0;

    for (int i = 0; i < npoint; ++i) {
        if (tid == 0) {
            outIdx[(size_t)b * npoint + i] = far;
            outXyz[((size_t)b * npoint + i) * 3 + 0] = cx;
            outXyz[((size_t)b * npoint + i) * 3 + 1] = cy;
            outXyz[((size_t)b * npoint + i) * 3 + 2] = cz;
        }
        float bestV = -1.0f;
        int bestW = 0;
#pragma unroll
        for (int w = 0; w < ITEMS; ++w) {
            float dx = __fsub_rn(px[w], cx);
            float dy = __fsub_rn(py[w], cy);
            float dz = __fsub_rn(pz[w], cz);
            float d = __fadd_rn(__fadd_rn(__fmul_rn(dx, dx), __fmul_rn(dy, dy)),
                                __fmul_rn(dz, dz));
            float dd = fminf(dloc[w], d);
            dloc[w] = dd;
            if (dd > bestV) { bestV = dd; bestW = w; }
        }
        int bestN = tid + bestW * 64;
        unsigned vmax, iInv;
        wave_argmax(__float_as_uint(bestV), 0xFFFFFFFFu ^ (unsigned)bestN,
                    vmax, iInv);
        far = (int)(0xFFFFFFFFu ^ iInv);
        float4 cc = scoord[far];
        cx = cc.x; cy = cc.y; cz = cc.z;
    }
}

// ---------------- fused query_ball + group for SA1 --------------------------
// One wave per center. Reference distance uses (c-p); we use e=(p-c): squares
// are bitwise identical, and e is exactly the grouped row value. Rows written
// in ascending point order (== sorted idx); rows beyond cnt padded with the
// first in-ball point's row. cnt >= 1 always (center is one of the points).
__global__ __launch_bounds__(256) void qb_group1(
    const float* __restrict__ xyz /*(8,4096,4)*/,
    const float* __restrict__ ctr /*(8*512,3)*/,
    float* __restrict__ out /*(8*512*32, 8)*/)
{
    int gw = (blockIdx.x * 256 + threadIdx.x) >> 6;
    int lane = threadIdx.x & 63;
    if (gw >= 4096) return;
    int b = gw >> 9;
    const float* P = xyz + (size_t)b * 4096 * 4;
    float cx = ctr[(size_t)gw * 3 + 0];
    float cy = ctr[(size_t)gw * 3 + 1];
    float cz = ctr[(size_t)gw * 3 + 2];
    float* out0 = out + (size_t)gw * 32 * 8;
    int cnt = 0;
    float f0x = 0.f, f0y = 0.f, f0z = 0.f, f0t = 0.f;
    bool haveFirst = false;
    for (int base = 0; base < 4096 && cnt < 32; base += 64) {
        int n = base + lane;
        float4 p = *(const float4*)(P + (size_t)n * 4);
        float ex = __fsub_rn(p.x, cx);
        float ey = __fsub_rn(p.y, cy);
        float ez = __fsub_rn(p.z, cz);
        float d = __fadd_rn(__fadd_rn(__fmul_rn(ex, ex), __fmul_rn(ey, ey)),
                            __fmul_rn(ez, ez));
        bool inb = !(d > 0.04f);
        unsigned long long mask = __ballot(inb);
        if (mask) {
            if (!haveFirst) {
                int fl = (int)__builtin_ctzll(mask);   // wave-uniform
                f0x = __shfl(ex, fl); f0y = __shfl(ey, fl);
                f0z = __shfl(ez, fl); f0t = __shfl(p.w, fl);
                haveFirst = true;
            }
            if (inb) {
                int pos = cnt + __builtin_popcountll(mask & ((1ull << lane) - 1ull));
                if (pos < 32) {
                    float* o = out0 + (size_t)pos * 8;
                    *(float4*)o = make_float4(ex, ey, ez, p.w);
                    *(float4*)(o + 4) = make_float4(0.f, 0.f, 0.f, 0.f);
                }
            }
            cnt += (int)__builtin_popcountll(mask);
        }
    }
    if (cnt > 32) cnt = 32;
    for (int p2 = cnt + lane; p2 < 32; p2 += 64) {
        float* o = out0 + (size_t)p2 * 8;
        *(float4*)o = make_float4(f0x, f0y, f0z, f0t);
        *(float4*)(o + 4) = make_float4(0.f, 0.f, 0.f, 0.f);
    }
}

// ---------------- query_ball (index-emitting, SA2) ----------------
__global__ __launch_bounds__(256) void query_ball_kernel(
    const float* __restrict__ xyz, int stride, int N,
    const float* __restrict__ centers, int nCenters, int S,
    float r2, int nsample, int* __restrict__ outIdx)
{
    int gw = (blockIdx.x * 256 + threadIdx.x) >> 6;
    int lane = threadIdx.x & 63;
    if (gw >= nCenters) return;
    int b = gw / S;
    const float* P = xyz + (size_t)b * N * stride;
    float cx = centers[(size_t)gw * 3 + 0];
    float cy = centers[(size_t)gw * 3 + 1];
    float cz = centers[(size_t)gw * 3 + 2];
    int* out = outIdx + (size_t)gw * nsample;
    int cnt = 0;
    int firstIdx = 0;
    bool haveFirst = false;
    for (int base = 0; base < N && cnt < nsample; base += 64) {
        int n = base + lane;
        bool inb = false;
        if (n < N) {
            float dx = __fsub_rn(cx, P[(size_t)n * stride + 0]);
            float dy = __fsub_rn(cy, P[(size_t)n * stride + 1]);
            float dz = __fsub_rn(cz, P[(size_t)n * stride + 2]);
            float d = __fadd_rn(__fadd_rn(__fmul_rn(dx, dx), __fmul_rn(dy, dy)),
                                __fmul_rn(dz, dz));
            inb = !(d > r2);
        }
        unsigned long long mask = __ballot(inb);
        if (mask) {
            if (!haveFirst) { firstIdx = base + __builtin_ctzll(mask); haveFirst = true; }
            if (inb) {
                int pos = cnt + __builtin_popcountll(mask & ((1ull << lane) - 1ull));
                if (pos < nsample) out[pos] = n;
            }
            cnt += (int)__builtin_popcountll(mask);
        }
    }
    if (cnt > nsample) cnt = nsample;
    for (int p = cnt + lane; p < nsample; p += 64) out[p] = firstIdx;
}

// ---------------- grouping kernels (f32, padded rows) ----------------------
__global__ __launch_bounds__(256) void group2_kernel(
    const float* __restrict__ xyz, const float* __restrict__ feat,
    const int* __restrict__ qb, const float* __restrict__ ctr,
    float* __restrict__ out)
{
    int i = blockIdx.x * 256 + threadIdx.x;
    if (i >= 65536 * 136) return;
    int sk = i / 136;
    int c = i - sk * 136;
    int b = sk / (128 * 64);
    int bs = sk / 64;
    int idx = qb[sk];
    idx = (idx < 0) ? 0 : (idx > 511 ? 511 : idx);
    float v = 0.f;
    if (c < 3)        v = __fsub_rn(xyz[((size_t)b * 512 + idx) * 3 + c], ctr[(size_t)bs * 3 + c]);
    else if (c < 131) v = feat[((size_t)b * 512 + idx) * 128 + (c - 3)];
    out[i] = v;
}

__global__ __launch_bounds__(256) void group3_kernel(
    const float* __restrict__ ctr2, const float* __restrict__ feat2,
    float* __restrict__ out)
{
    int i = blockIdx.x * 256 + threadIdx.x;
    if (i >= 1024 * 264) return;
    int sk = i / 264;
    int c = i - sk * 264;
    float v = 0.f;
    if (c < 3)        v = ctr2[(size_t)sk * 3 + c];
    else if (c < 259) v = feat2[(size_t)sk * 256 + (c - 3)];
    out[i] = v;
}

// ---------------- all-layer weight pre-split ----------------
struct PWArgs {
    const float* w[9];
    unsigned off[9];
    int O[9], C[9], CP[9];
};
__global__ __launch_bounds__(256) void prep_w_all(
    PWArgs a, unsigned short* __restrict__ wh, unsigned short* __restrict__ wl,
    int total)
{
    int i = blockIdx.x * 256 + threadIdx.x;
    if (i >= total) return;
    int l = 0;
#pragma unroll
    for (int k = 1; k < 9; ++k) if (i >= (int)a.off[k]) l = k;
    int li = i - (int)a.off[l];
    int CP = a.CP[l];
    int o = li / CP;
    int c = li - o * CP;
    float v = (c < a.C[l]) ? a.w[l][(size_t)o * a.C[l] + c] : 0.f;
    unsigned short h, lo;
    f2bf_split(v, h, lo);
    wh[i] = h; wl[i] = lo;
}

// ---------------- fused GEMM: Y = act(X) * W^T  (+ BN stats) ---------------
// X f32 [M, AC]; act (BN of PREVIOUS layer) + hi/lo bf16 split in staging.
// W pre-split padded planes [O, CPW]. D = Ah*Bl + Al*Bh + Ah*Bh (ascending
// k0) — same rounding as R6-R9. Epilogue: deterministic per-block per-channel
// sum/sumsq -> part[o*YB + bx] (+O*YB for sumsq), YB = gridDim.x.
// Block 128x128, 4 waves 64x64 quadrants, 4x4 16x16x32 mfma, BK=32,
// LDS pitch 40 (aligned b128 frags, <=2-way banks). M%128==0, AC%4==0.
__global__ __launch_bounds__(256) void gemm_fused(
    const float* __restrict__ X,
    const float* __restrict__ scale, const float* __restrict__ shift,
    int applyAct,
    const unsigned short* __restrict__ Bh, const unsigned short* __restrict__ Bl,
    float* __restrict__ Y, double* __restrict__ part,
    int M, int AC, int CPW, int O)
{
    constexpr int PITCH = 40;
    __shared__ __align__(16) unsigned short sAh[128 * PITCH];
    __shared__ __align__(16) unsigned short sAl[128 * PITCH];
    __shared__ __align__(16) unsigned short sBh[128 * PITCH];
    __shared__ __align__(16) unsigned short sBl[128 * PITCH];
    __shared__ float sred[2048];

    const int tid = threadIdx.x;
    const int lane = tid & 63;
    const int wid = tid >> 6;
    const int col15 = lane & 15;
    const int quad = lane >> 4;
    const int wm = (wid >> 1) * 64;
    const int wo = (wid & 1) * 64;
    const int m0 = blockIdx.x * 128;
    const int o0 = blockIdx.y * 128;
    const int YB = gridDim.x;
    const int lr = tid >> 2;
    const int lc = (tid & 3) * 8;

    f32x4 acc[4][4];
#pragma unroll
    for (int mt = 0; mt < 4; ++mt)
#pragma unroll
        for (int ot = 0; ot < 4; ++ot)
            acc[mt][ot] = {0.f, 0.f, 0.f, 0.f};

    for (int k0 = 0; k0 < CPW; k0 += 32) {
#pragma unroll
        for (int it = 0; it < 2; ++it) {
            int r = lr + it * 64;
            int c = k0 + lc;
            unsigned short h[8], l[8];
            if (c + 8 <= AC) {
                const float* xr = X + (size_t)(m0 + r) * AC + c;
                float4 v0 = *(const float4*)xr;
                float4 v1 = *(const float4*)(xr + 4);
                float vv[8] = {v0.x, v0.y, v0.z, v0.w, v1.x, v1.y, v1.z, v1.w};
#pragma unroll
                for (int j = 0; j < 8; ++j) {
                    float v = vv[j];
                    if (applyAct) v = fmaxf(v * scale[c + j] + shift[c + j], 0.f);
                    f2bf_split(v, h[j], l[j]);
                }
            } else {
#pragma unroll
                for (int j = 0; j < 8; ++j) { h[j] = 0; l[j] = 0; }
            }
            *(ushort4*)&sAh[r * PITCH + lc] = make_ushort4(h[0], h[1], h[2], h[3]);
            *(ushort4*)&sAh[r * PITCH + lc + 4] = make_ushort4(h[4], h[5], h[6], h[7]);
            *(ushort4*)&sAl[r * PITCH + lc] = make_ushort4(l[0], l[1], l[2], l[3]);
            *(ushort4*)&sAl[r * PITCH + lc + 4] = make_ushort4(l[4], l[5], l[6], l[7]);
        }
#pragma unroll
        for (int it = 0; it < 2; ++it) {
            int r = lr + it * 64;
            int c = k0 + lc;
            int o = o0 + r;
            uint4 vh = {0, 0, 0, 0}, vl = {0, 0, 0, 0};
            if (o < O && c < CPW) {
                size_t goff = (size_t)o * CPW + c;
                vh = *(const uint4*)(Bh + goff);
                vl = *(const uint4*)(Bl + goff);
            }
            *(uint4*)&sBh[r * PITCH + lc] = vh;
            *(uint4*)&sBl[r * PITCH + lc] = vl;
        }
        __syncthreads();
        s16x8 ah[4], al[4], bh[4], bl[4];
#pragma unroll
        for (int mt = 0; mt < 4; ++mt) {
            int rowoff = (wm + mt * 16 + col15) * PITCH + quad * 8;
            ah[mt] = *(const s16x8*)&sAh[rowoff];
            al[mt] = *(const s16x8*)&sAl[rowoff];
        }
#pragma unroll
        for (int ot = 0; ot < 4; ++ot) {
            int rowoff = (wo + ot * 16 + col15) * PITCH + quad * 8;
            bh[ot] = *(const s16x8*)&sBh[rowoff];
            bl[ot] = *(const s16x8*)&sBl[rowoff];
        }
#pragma unroll
        for (int mt = 0; mt < 4; ++mt)
#pragma unroll
            for (int ot = 0; ot < 4; ++ot) {
                acc[mt][ot] = __builtin_amdgcn_mfma_f32_16x16x32_bf16(
                    ah[mt], bl[ot], acc[mt][ot], 0, 0, 0);
                acc[mt][ot] = __builtin_amdgcn_mfma_f32_16x16x32_bf16(
                    al[mt], bh[ot], acc[mt][ot], 0, 0, 0);
                acc[mt][ot] = __builtin_amdgcn_mfma_f32_16x16x32_bf16(
                    ah[mt], bh[ot], acc[mt][ot], 0, 0, 0);
            }
        __syncthreads();
    }
#pragma unroll
    for (int mt = 0; mt < 4; ++mt)
#pragma unroll
        for (int ot = 0; ot < 4; ++ot) {
            int og = o0 + wo + ot * 16 + col15;
            if (og < O) {
#pragma unroll
                for (int r = 0; r < 4; ++r) {
                    int mg = m0 + wm + mt * 16 + quad * 4 + r;
                    Y[(size_t)mg * O + og] = acc[mt][ot][r];
                }
            }
        }
    // BN stats epilogue (deterministic fixed-order combine).
#pragma unroll
    for (int ot = 0; ot < 4; ++ot) {
        float s = 0.f, s2 = 0.f;
#pragma unroll
        for (int mt = 0; mt < 4; ++mt)
#pragma unroll
            for (int r = 0; r < 4; ++r) {
                float v = acc[mt][ot][r];
                s += v;
                s2 += v * v;
            }
        int slot = ((wid * 4 + quad) * 16 + col15) * 4 + ot;
        sred[slot * 2] = s;
        sred[slot * 2 + 1] = s2;
    }
    __syncthreads();
    if (tid < 128) {
        int col = tid;
        int o = o0 + col;
        if (o < O) {
            int cb = col >> 6;
            int ot = (col & 63) >> 4;
            int c15 = col & 15;
            double S = 0.0, S2 = 0.0;
#pragma unroll
            for (int wp = 0; wp < 2; ++wp) {
                int wd = cb + wp * 2;
#pragma unroll
                for (int q = 0; q < 4; ++q) {
                    int slot = ((wd * 4 + q) * 16 + c15) * 4 + ot;
                    S += (double)sred[slot * 2];
                    S2 += (double)sred[slot * 2 + 1];
                }
            }
            part[(size_t)o * YB + blockIdx.x] = S;
            part[(size_t)O * YB + (size_t)o * YB + blockIdx.x] = S2;
        }
    }
}

// ---------------- finalize BN: one block per channel (parallel, coalesced) --
__global__ __launch_bounds__(256) void finalize_bn(
    const double* __restrict__ part, const float* __restrict__ g,
    const float* __restrict__ bb, float* __restrict__ scale,
    float* __restrict__ shift, int O, int YB, double invM)
{
    int o = blockIdx.x;
    int tid = threadIdx.x;
    double s = 0.0, s2 = 0.0;
    for (int yb = tid; yb < YB; yb += 256) {
        s  += part[(size_t)o * YB + yb];
        s2 += part[(size_t)O * YB + (size_t)o * YB + yb];
    }
    __shared__ double sd[512];
    sd[tid] = s;
    sd[256 + tid] = s2;
    __syncthreads();
#pragma unroll
    for (int st = 128; st > 0; st >>= 1) {
        if (tid < st) {
            sd[tid] += sd[tid + st];
            sd[256 + tid] += sd[256 + tid + st];
        }
        __syncthreads();
    }
    if (tid == 0) {
        double mean = sd[0] * invM;
        double var = sd[256] * invM - mean * mean;
        float varf = (float)var;
        if (varf < 0.f) varf = 0.f;
        float sc = g[o] * rsqrtf(varf + 1e-5f);
        scale[o] = sc;
        shift[o] = bb[o] - (float)mean * sc;
    }
}

// ---------------- BN + ReLU + max over K ----------------
__global__ __launch_bounds__(256) void bn_relu_max(
    const float* __restrict__ Y, const float* __restrict__ scale,
    const float* __restrict__ shift, float* __restrict__ out,
    int Stot, int K, int O)
{
    int idx = blockIdx.x * 256 + threadIdx.x;
    if (idx >= Stot * O) return;
    int s = idx / O;
    int o = idx - s * O;
    const float* base = Y + (size_t)s * K * O + o;
    float sc = scale[o], sh = shift[o];
    float mx = 0.f;
    for (int k = 0; k < K; ++k) {
        float v = base[(size_t)k * O] * sc + sh;
        v = fmaxf(v, 0.f);
        mx = fmaxf(mx, v);
    }
    out[idx] = mx;
}

// ============================================================================
extern "C" void kernel_launch(void* const* d_in, const int* in_sizes, int n_in,
                              void* d_out, int out_size, void* d_ws, size_t ws_size,
                              hipStream_t stream)
{
    const float* xin = (const float*)d_in[0];
    const float* w[9]; const float* g[9]; const float* bb[9];
    for (int i = 0; i < 9; ++i) {
        w[i]  = (const float*)d_in[1 + 3 * i];
        g[i]  = (const float*)d_in[2 + 3 * i];
        bb[i] = (const float*)d_in[3 + 3 * i];
    }

    char* base = (char*)d_ws;
    size_t off = 0;
    auto alloc = [&](size_t bytes) -> void* {
        void* p = base + off;
        off = (off + bytes + 255) & ~(size_t)255;
        return p;
    };
    const int OC[9][3] = {{64,4,8},{64,64,64},{128,64,64},
                          {128,131,136},{128,128,128},{256,128,128},
                          {256,259,264},{512,256,256},{1024,512,512}};
    size_t woff[10]; woff[0] = 0;
    for (int i = 0; i < 9; ++i) woff[i + 1] = woff[i] + (size_t)OC[i][0] * OC[i][2];

    // --- small / metadata region (memset-protected) ---
    int*    fps1   = (int*)alloc((size_t)4096 * 4);
    int*    fps2   = (int*)alloc((size_t)1024 * 4);
    int*    qb2    = (int*)alloc((size_t)65536 * 4);
    float*  nx1    = (float*)alloc((size_t)12288 * 4);
    float*  nx2    = (float*)alloc((size_t)3072 * 4);
    float*  feat1  = (float*)alloc((size_t)524288 * 4);
    float*  feat2  = (float*)alloc((size_t)262144 * 4);
    double* part   = (double*)alloc((size_t)262144 * 8);
    float*  scales = (float*)alloc((size_t)9 * 1024 * 4);
    float*  shifts = (float*)alloc((size_t)9 * 1024 * 4);
    unsigned short* WH = (unsigned short*)alloc(woff[9] * 2);
    unsigned short* WL = (unsigned short*)alloc(woff[9] * 2);
    const size_t zeroBytes = off;
    // --- big ping/pong buffers: verified fully-written-before-read at every
    //     use (group*/gemm write the exact region the next consumer reads) ---
    float*  XG = (float*)alloc((size_t)65536 * 136 * 4);
    float*  A  = (float*)alloc((size_t)16777216 * 4);
    if (off > ws_size) return;

    // Defensive zero of the metadata region only (~5 MB): keeps every call
    // bit-identical regardless of harness ws poison for all index/stat paths.
    hipMemsetAsync(d_ws, 0, zeroBytes, stream);

    PWArgs pwa;
    for (int i = 0; i < 9; ++i) {
        pwa.w[i] = w[i]; pwa.off[i] = (unsigned)woff[i];
        pwa.O[i] = OC[i][0]; pwa.C[i] = OC[i][1]; pwa.CP[i] = OC[i][2];
    }
    prep_w_all<<<(int)((woff[9] + 255) / 256), 256, 0, stream>>>(pwa, WH, WL, (int)woff[9]);

    // ---------------- SA1 ----------------
    fps_block<256, 16, 4><<<8, 256, 0, stream>>>(xin, 512, fps1, nx1);
    qb_group1<<<(4096 * 64) / 256, 256, 0, stream>>>(xin, nx1, XG);

    // L1_0: (131072, AC=8) -> 64
    gemm_fused<<<dim3(1024, 1), 256, 0, stream>>>(XG, nullptr, nullptr, 0, WH + woff[0], WL + woff[0], A, part, 131072, 8, 8, 64);
    finalize_bn<<<64, 256, 0, stream>>>(part, g[0], bb[0], scales + 0 * 1024, shifts + 0 * 1024, 64, 1024, 1.0 / 131072.0);
    // L1_1: 64 -> 64
    gemm_fused<<<dim3(1024, 1), 256, 0, stream>>>(A, scales + 0 * 1024, shifts + 0 * 1024, 1, WH + woff[1], WL + woff[1], XG, part, 131072, 64, 64, 64);
    finalize_bn<<<64, 256, 0, stream>>>(part, g[1], bb[1], scales + 1 * 1024, shifts + 1 * 1024, 64, 1024, 1.0 / 131072.0);
    // L1_2: 64 -> 128
    gemm_fused<<<dim3(1024, 1), 256, 0, stream>>>(XG, scales + 1 * 1024, shifts + 1 * 1024, 1, WH + woff[2], WL + woff[2], A, part, 131072, 64, 64, 128);
    finalize_bn<<<128, 256, 0, stream>>>(part, g[2], bb[2], scales + 2 * 1024, shifts + 2 * 1024, 128, 1024, 1.0 / 131072.0);
    bn_relu_max<<<(4096 * 128) / 256, 256, 0, stream>>>(A, scales + 2 * 1024, shifts + 2 * 1024, feat1, 4096, 32, 128);

    // ---------------- SA2 ----------------
    fps_wave<8, 3><<<8, 64, 0, stream>>>(nx1, 128, fps2, nx2);
    query_ball_kernel<<<(8 * 128 * 64) / 256, 256, 0, stream>>>(
        nx1, 3, 512, nx2, 8 * 128, 128, 0.16f, 64, qb2);
    group2_kernel<<<(65536 * 136) / 256, 256, 0, stream>>>(nx1, feat1, qb2, nx2, XG);

    // L2_0: (65536, AC=136) -> 128
    gemm_fused<<<dim3(512, 1), 256, 0, stream>>>(XG, nullptr, nullptr, 0, WH + woff[3], WL + woff[3], A, part, 65536, 136, 136, 128);
    finalize_bn<<<128, 256, 0, stream>>>(part, g[3], bb[3], scales + 3 * 1024, shifts + 3 * 1024, 128, 512, 1.0 / 65536.0);
    // L2_1: 128 -> 128
    gemm_fused<<<dim3(512, 1), 256, 0, stream>>>(A, scales + 3 * 1024, shifts + 3 * 1024, 1, WH + woff[4], WL + woff[4], XG, part, 65536, 128, 128, 128);
    finalize_bn<<<128, 256, 0, stream>>>(part, g[4], bb[4], scales + 4 * 1024, shifts + 4 * 1024, 128, 512, 1.0 / 65536.0);
    // L2_2: 128 -> 256
    gemm_fused<<<dim3(512, 2), 256, 0, stream>>>(XG, scales + 4 * 1024, shifts + 4 * 1024, 1, WH + woff[5], WL + woff[5], A, part, 65536, 128, 128, 256);
    finalize_bn<<<256, 256, 0, stream>>>(part, g[5], bb[5], scales + 5 * 1024, shifts + 5 * 1024, 256, 512, 1.0 / 65536.0);
    bn_relu_max<<<(1024 * 256) / 256, 256, 0, stream>>>(A, scales + 5 * 1024, shifts + 5 * 1024, feat2, 1024, 64, 256);

    // ---------------- SA3 (group_all) ----------------
    group3_kernel<<<(1024 * 264) / 256, 256, 0, stream>>>(nx2, feat2, XG);

    // L3_0: (1024, AC=264) -> 256
    gemm_fused<<<dim3(8, 2), 256, 0, stream>>>(XG, nullptr, nullptr, 0, WH + woff[6], WL + woff[6], A, part, 1024, 264, 264, 256);
    finalize_bn<<<256, 256, 0, stream>>>(part, g[6], bb[6], scales + 6 * 1024, shifts + 6 * 1024, 256, 8, 1.0 / 1024.0);
    // L3_1: 256 -> 512
    gemm_fused<<<dim3(8, 4), 256, 0, stream>>>(A, scales + 6 * 1024, shifts + 6 * 1024, 1, WH + woff[7], WL + woff[7], XG, part, 1024, 256, 256, 512);
    finalize_bn<<<512, 256, 0, stream>>>(part, g[7], bb[7], scales + 7 * 1024, shifts + 7 * 1024, 512, 8, 1.0 / 1024.0);
    // L3_2: 512 -> 1024
    gemm_fused<<<dim3(8, 8), 256, 0, stream>>>(XG, scales + 7 * 1024, shifts + 7 * 1024, 1, WH + woff[8], WL + woff[8], A, part, 1024, 512, 512, 1024);
    finalize_bn<<<1024, 256, 0, stream>>>(part, g[8], bb[8], scales + 8 * 1024, shifts + 8 * 1024, 1024, 8, 1.0 / 1024.0);
    bn_relu_max<<<(8 * 1024) / 256, 256, 0, stream>>>(A, scales + 8 * 1024, shifts + 8 * 1024, (float*)d_out, 8, 128, 1024);
}

// Round 11
// 833.677 us; speedup vs baseline: 1.1530x; 1.1530x over previous
//
#include <hip/hip_runtime.h>

// ============================================================================
// TemporalPointNet (PointNet++ style) forward on MI355X.
// B=2, T=4 -> BT=8 "batches", N=4096 points, 4 coords (xyz + t).
// SA1: npoint=512, r=0.2, K=32, C_in=4,  MLP 64,64,128
// SA2: npoint=128, r=0.4, K=64, C_in=131, MLP 128,128,256
// SA3: group_all,          K=128, C_in=259, MLP 256,512,1024
// Output: (2,4,1024) f32 = 8192 floats.
//
// R11: surgical revert of R10's lexicographic 64-bit DPP chain (measured
// +99us on fps_block: 2 DPP + 64-bit cmp + 2 cndmask per step on the critical
// chain beats doubling the step count). Restored R9's two 32-bit DPP chains.
// Keeps R10's wins: qb+group1 fusion, metadata-only memset, 28 dispatches.
// GEMM: split-bf16 triple MFMA + fused BN stats epilogue (absmax 0.03125).
// ============================================================================

typedef short s16x8 __attribute__((ext_vector_type(8)));
typedef float f32x4 __attribute__((ext_vector_type(4)));

__device__ __forceinline__ unsigned short f2bf_rne(float f) {
    unsigned u = __float_as_uint(f);
    u += 0x7FFFu + ((u >> 16) & 1u);
    return (unsigned short)(u >> 16);
}
// split f32 -> (hi, lo) bf16 pair: hi = rne(v), lo = rne(v - hi)
__device__ __forceinline__ void f2bf_split(float v, unsigned short& hi,
                                           unsigned short& lo) {
    unsigned u = __float_as_uint(v);
    unsigned r = u + 0x7FFFu + ((u >> 16) & 1u);
    hi = (unsigned short)(r >> 16);
    float vh = __uint_as_float(r & 0xFFFF0000u);
    lo = f2bf_rne(v - vh);
}

__device__ __forceinline__ unsigned long long umax64(unsigned long long a,
                                                     unsigned long long b) {
    return a > b ? a : b;
}

// Wave64 max-reduce via DPP (LLVM atomic-optimizer sequence): 1 DPP + 1 max
// per step — minimal critical-chain depth (R9 measured-best; R10's fused
// 64-bit variant regressed +99us). Result valid in lane 63.
__device__ __forceinline__ unsigned wred_umax63(unsigned v) {
    unsigned t;
    t = (unsigned)__builtin_amdgcn_update_dpp(0, (int)v, 0x111, 0xf, 0xf, true); if (t > v) v = t;
    t = (unsigned)__builtin_amdgcn_update_dpp(0, (int)v, 0x112, 0xf, 0xf, true); if (t > v) v = t;
    t = (unsigned)__builtin_amdgcn_update_dpp(0, (int)v, 0x114, 0xf, 0xf, true); if (t > v) v = t;
    t = (unsigned)__builtin_amdgcn_update_dpp(0, (int)v, 0x118, 0xf, 0xf, true); if (t > v) v = t;
    t = (unsigned)__builtin_amdgcn_update_dpp(0, (int)v, 0x142, 0xa, 0xf, true); if (t > v) v = t;
    t = (unsigned)__builtin_amdgcn_update_dpp(0, (int)v, 0x143, 0xc, 0xf, true); if (t > v) v = t;
    return v;
}

// Wave argmax of (dist, min-index). dist >= 0 -> float bit order == value
// order; nInv = ~n -> max picks lowest index. Exact first-occurrence argmax.
__device__ __forceinline__ void wave_argmax(unsigned dbits, unsigned nInv,
                                            unsigned& vmax, unsigned& iInv) {
    unsigned m = wred_umax63(dbits);
    vmax = (unsigned)__builtin_amdgcn_readlane((int)m, 63);
    unsigned cand = (dbits == vmax) ? nInv : 0u;
    unsigned im = wred_umax63(cand);
    iInv = (unsigned)__builtin_amdgcn_readlane((int)im, 63);
}

// ---------------- FPS (multi-wave): one block (NT thr) per batch ------------
// R7/R9 structure (measured best 286us): scoord table + per-wave u64 keys;
// combine = NW u64 reads + one broadcast b128. jnp semantics: dist init 1e10,
// d = ((dx^2+dy^2)+dz^2) rn ops (no fma), argmax = FIRST occurrence of max.
template<int NT, int ITEMS, int STRIDE>
__global__ __launch_bounds__(NT) void fps_block(
    const float* __restrict__ pts, int npoint,
    int* __restrict__ outIdx, float* __restrict__ outXyz)
{
    constexpr int N = NT * ITEMS;
    constexpr int NW = NT / 64;
    __shared__ float4 scoord[N];
    __shared__ unsigned long long wkey[2][NW];

    const int b = blockIdx.x;
    const int tid = threadIdx.x;
    const int wid = tid >> 6;
    const int lane = tid & 63;
    const float* P = pts + (size_t)b * N * STRIDE;

    float px[ITEMS], py[ITEMS], pz[ITEMS], dloc[ITEMS];
#pragma unroll
    for (int w = 0; w < ITEMS; ++w) {
        int n = tid + w * NT;
        float x, y, z;
        if (STRIDE == 4) {
            float4 v = *(const float4*)(P + (size_t)n * 4);
            x = v.x; y = v.y; z = v.z;
        } else {
            x = P[(size_t)n * STRIDE + 0];
            y = P[(size_t)n * STRIDE + 1];
            z = P[(size_t)n * STRIDE + 2];
        }
        px[w] = x; py[w] = y; pz[w] = z;
        scoord[n] = make_float4(x, y, z, 0.f);
        dloc[w] = 1e10f;
    }
    __syncthreads();
    float4 c0 = scoord[0];
    float cx = c0.x, cy = c0.y, cz = c0.z;
    int far = 0;

    for (int i = 0; i < npoint; ++i) {
        if (tid == 0) {
            outIdx[(size_t)b * npoint + i] = far;
            outXyz[((size_t)b * npoint + i) * 3 + 0] = cx;
            outXyz[((size_t)b * npoint + i) * 3 + 1] = cy;
            outXyz[((size_t)b * npoint + i) * 3 + 2] = cz;
        }
        float bestV = -1.0f;
        int bestW = 0;
#pragma unroll
        for (int w = 0; w < ITEMS; ++w) {
            float dx = __fsub_rn(px[w], cx);
            float dy = __fsub_rn(py[w], cy);
            float dz = __fsub_rn(pz[w], cz);
            float d = __fadd_rn(__fadd_rn(__fmul_rn(dx, dx), __fmul_rn(dy, dy)),
                                __fmul_rn(dz, dz));
            float dd = fminf(dloc[w], d);
            dloc[w] = dd;
            if (dd > bestV) { bestV = dd; bestW = w; }  // strict > : lowest w kept
        }
        int bestN = tid + bestW * NT;   // n grows with w -> min n on tie
        unsigned vmax, iInv;
        wave_argmax(__float_as_uint(bestV), 0xFFFFFFFFu ^ (unsigned)bestN,
                    vmax, iInv);
        const int par = i & 1;
        if (lane == 0)
            wkey[par][wid] = ((unsigned long long)vmax << 32) | iInv;
        __syncthreads();   // single barrier per iteration (parity dbuf)
        unsigned long long kb = wkey[par][0];
#pragma unroll
        for (int w2 = 1; w2 < NW; ++w2) kb = umax64(kb, wkey[par][w2]);
        far = (int)(0xFFFFFFFFu ^ (unsigned)kb);
        float4 cc = scoord[far];   // broadcast, conflict-free
        cx = cc.x; cy = cc.y; cz = cc.z;
    }
}

// ---------------- FPS (single wave): no barriers at all ---------------------
template<int ITEMS, int STRIDE>
__global__ __launch_bounds__(64) void fps_wave(
    const float* __restrict__ pts, int npoint,
    int* __restrict__ outIdx, float* __restrict__ outXyz)
{
    constexpr int N = 64 * ITEMS;
    __shared__ float4 scoord[N];

    const int b = blockIdx.x;
    const int tid = threadIdx.x;
    const float* P = pts + (size_t)b * N * STRIDE;

    float px[ITEMS], py[ITEMS], pz[ITEMS], dloc[ITEMS];
#pragma unroll
    for (int w = 0; w < ITEMS; ++w) {
        int n = tid + w * 64;
        float x = P[(size_t)n * STRIDE + 0];
        float y = P[(size_t)n * STRIDE + 1];
        float z = P[(size_t)n * STRIDE + 2];
        px[w] = x; py[w] = y; pz[w] = z;
        scoord[n] = make_float4(x, y, z, 0.f);
        dloc[w] = 1e10f;
    }
    __syncthreads();
    float4 c0 = scoord[0];
    float cx = c0.x, cy = c0.y, cz = c0.z;
    int far = 0;

    for (int i = 0; i < npoint; ++i) {
        if (tid == 0) {
            outIdx[(size_t)b * npoint + i] = far;
            outXyz[((size_t)b * npoint + i) * 3 + 0] = cx;
            outXyz[((size_t)b * npoint + i) * 3 + 1] = cy;
            outXyz[((size_t)b * npoint + i) * 3 + 2] = cz;
        }
        float bestV = -1.0f;
        int bestW = 0;
#pragma unroll
        for (int w = 0; w < ITEMS; ++w) {
            float dx = __fsub_rn(px[w], cx);
            float dy = __fsub_rn(py[w], cy);
            float dz = __fsub_rn(pz[w], cz);
            float d = __fadd_rn(__fadd_rn(__fmul_rn(dx, dx), __fmul_rn(dy, dy)),
                                __fmul_rn(dz, dz));
            float dd = fminf(dloc[w], d);
            dloc[w] = dd;
            if (dd > bestV) { bestV = dd; bestW = w; }
        }
        int bestN = tid + bestW * 64;
        unsigned vmax, iInv;
        wave_argmax(__float_as_uint(bestV), 0xFFFFFFFFu ^ (unsigned)bestN,
                    vmax, iInv);
        far = (int)(0xFFFFFFFFu ^ iInv);
        float4 cc = scoord[far];
        cx = cc.x; cy = cc.y; cz = cc.z;
    }
}

// ---------------- fused query_ball + group for SA1 --------------------------
// One wave per center. Reference distance uses (c-p); we use e=(p-c): squares
// are bitwise identical, and e is exactly the grouped row value. Rows written
// in ascending point order (== sorted idx); rows beyond cnt padded with the
// first in-ball point's row. cnt >= 1 always (center is one of the points).
__global__ __launch_bounds__(256) void qb_group1(
    const float* __restrict__ xyz /*(8,4096,4)*/,
    const float* __restrict__ ctr /*(8*512,3)*/,
    float* __restrict__ out /*(8*512*32, 8)*/)
{
    int gw = (blockIdx.x * 256 + threadIdx.x) >> 6;
    int lane = threadIdx.x & 63;
    if (gw >= 4096) return;
    int b = gw >> 9;
    const float* P = xyz + (size_t)b * 4096 * 4;
    float cx = ctr[(size_t)gw * 3 + 0];
    float cy = ctr[(size_t)gw * 3 + 1];
    float cz = ctr[(size_t)gw * 3 + 2];
    float* out0 = out + (size_t)gw * 32 * 8;
    int cnt = 0;
    float f0x = 0.f, f0y = 0.f, f0z = 0.f, f0t = 0.f;
    bool haveFirst = false;
    for (int base = 0; base < 4096 && cnt < 32; base += 64) {
        int n = base + lane;
        float4 p = *(const float4*)(P + (size_t)n * 4);
        float ex = __fsub_rn(p.x, cx);
        float ey = __fsub_rn(p.y, cy);
        float ez = __fsub_rn(p.z, cz);
        float d = __fadd_rn(__fadd_rn(__fmul_rn(ex, ex), __fmul_rn(ey, ey)),
                            __fmul_rn(ez, ez));
        bool inb = !(d > 0.04f);
        unsigned long long mask = __ballot(inb);
        if (mask) {
            if (!haveFirst) {
                int fl = (int)__builtin_ctzll(mask);   // wave-uniform
                f0x = __shfl(ex, fl); f0y = __shfl(ey, fl);
                f0z = __shfl(ez, fl); f0t = __shfl(p.w, fl);
                haveFirst = true;
            }
            if (inb) {
                int pos = cnt + __builtin_popcountll(mask & ((1ull << lane) - 1ull));
                if (pos < 32) {
                    float* o = out0 + (size_t)pos * 8;
                    *(float4*)o = make_float4(ex, ey, ez, p.w);
                    *(float4*)(o + 4) = make_float4(0.f, 0.f, 0.f, 0.f);
                }
            }
            cnt += (int)__builtin_popcountll(mask);
        }
    }
    if (cnt > 32) cnt = 32;
    for (int p2 = cnt + lane; p2 < 32; p2 += 64) {
        float* o = out0 + (size_t)p2 * 8;
        *(float4*)o = make_float4(f0x, f0y, f0z, f0t);
        *(float4*)(o + 4) = make_float4(0.f, 0.f, 0.f, 0.f);
    }
}

// ---------------- query_ball (index-emitting, SA2) ----------------
__global__ __launch_bounds__(256) void query_ball_kernel(
    const float* __restrict__ xyz, int stride, int N,
    const float* __restrict__ centers, int nCenters, int S,
    float r2, int nsample, int* __restrict__ outIdx)
{
    int gw = (blockIdx.x * 256 + threadIdx.x) >> 6;
    int lane = threadIdx.x & 63;
    if (gw >= nCenters) return;
    int b = gw / S;
    const float* P = xyz + (size_t)b * N * stride;
    float cx = centers[(size_t)gw * 3 + 0];
    float cy = centers[(size_t)gw * 3 + 1];
    float cz = centers[(size_t)gw * 3 + 2];
    int* out = outIdx + (size_t)gw * nsample;
    int cnt = 0;
    int firstIdx = 0;
    bool haveFirst = false;
    for (int base = 0; base < N && cnt < nsample; base += 64) {
        int n = base + lane;
        bool inb = false;
        if (n < N) {
            float dx = __fsub_rn(cx, P[(size_t)n * stride + 0]);
            float dy = __fsub_rn(cy, P[(size_t)n * stride + 1]);
            float dz = __fsub_rn(cz, P[(size_t)n * stride + 2]);
            float d = __fadd_rn(__fadd_rn(__fmul_rn(dx, dx), __fmul_rn(dy, dy)),
                                __fmul_rn(dz, dz));
            inb = !(d > r2);
        }
        unsigned long long mask = __ballot(inb);
        if (mask) {
            if (!haveFirst) { firstIdx = base + __builtin_ctzll(mask); haveFirst = true; }
            if (inb) {
                int pos = cnt + __builtin_popcountll(mask & ((1ull << lane) - 1ull));
                if (pos < nsample) out[pos] = n;
            }
            cnt += (int)__builtin_popcountll(mask);
        }
    }
    if (cnt > nsample) cnt = nsample;
    for (int p = cnt + lane; p < nsample; p += 64) out[p] = firstIdx;
}

// ---------------- grouping kernels (f32, padded rows) ----------------------
__global__ __launch_bounds__(256) void group2_kernel(
    const float* __restrict__ xyz, const float* __restrict__ feat,
    const int* __restrict__ qb, const float* __restrict__ ctr,
    float* __restrict__ out)
{
    int i = blockIdx.x * 256 + threadIdx.x;
    if (i >= 65536 * 136) return;
    int sk = i / 136;
    int c = i - sk * 136;
    int b = sk / (128 * 64);
    int bs = sk / 64;
    int idx = qb[sk];
    idx = (idx < 0) ? 0 : (idx > 511 ? 511 : idx);
    float v = 0.f;
    if (c < 3)        v = __fsub_rn(xyz[((size_t)b * 512 + idx) * 3 + c], ctr[(size_t)bs * 3 + c]);
    else if (c < 131) v = feat[((size_t)b * 512 + idx) * 128 + (c - 3)];
    out[i] = v;
}

__global__ __launch_bounds__(256) void group3_kernel(
    const float* __restrict__ ctr2, const float* __restrict__ feat2,
    float* __restrict__ out)
{
    int i = blockIdx.x * 256 + threadIdx.x;
    if (i >= 1024 * 264) return;
    int sk = i / 264;
    int c = i - sk * 264;
    float v = 0.f;
    if (c < 3)        v = ctr2[(size_t)sk * 3 + c];
    else if (c < 259) v = feat2[(size_t)sk * 256 + (c - 3)];
    out[i] = v;
}

// ---------------- all-layer weight pre-split ----------------
struct PWArgs {
    const float* w[9];
    unsigned off[9];
    int O[9], C[9], CP[9];
};
__global__ __launch_bounds__(256) void prep_w_all(
    PWArgs a, unsigned short* __restrict__ wh, unsigned short* __restrict__ wl,
    int total)
{
    int i = blockIdx.x * 256 + threadIdx.x;
    if (i >= total) return;
    int l = 0;
#pragma unroll
    for (int k = 1; k < 9; ++k) if (i >= (int)a.off[k]) l = k;
    int li = i - (int)a.off[l];
    int CP = a.CP[l];
    int o = li / CP;
    int c = li - o * CP;
    float v = (c < a.C[l]) ? a.w[l][(size_t)o * a.C[l] + c] : 0.f;
    unsigned short h, lo;
    f2bf_split(v, h, lo);
    wh[i] = h; wl[i] = lo;
}

// ---------------- fused GEMM: Y = act(X) * W^T  (+ BN stats) ---------------
// X f32 [M, AC]; act (BN of PREVIOUS layer) + hi/lo bf16 split in staging.
// W pre-split padded planes [O, CPW]. D = Ah*Bl + Al*Bh + Ah*Bh (ascending
// k0) — same rounding as R6-R10. Epilogue: deterministic per-block
// per-channel sum/sumsq -> part[o*YB + bx] (+O*YB for sumsq), YB = gridDim.x.
// Block 128x128, 4 waves 64x64 quadrants, 4x4 16x16x32 mfma, BK=32,
// LDS pitch 40 (aligned b128 frags, <=2-way banks). M%128==0, AC%4==0.
__global__ __launch_bounds__(256) void gemm_fused(
    const float* __restrict__ X,
    const float* __restrict__ scale, const float* __restrict__ shift,
    int applyAct,
    const unsigned short* __restrict__ Bh, const unsigned short* __restrict__ Bl,
    float* __restrict__ Y, double* __restrict__ part,
    int M, int AC, int CPW, int O)
{
    constexpr int PITCH = 40;
    __shared__ __align__(16) unsigned short sAh[128 * PITCH];
    __shared__ __align__(16) unsigned short sAl[128 * PITCH];
    __shared__ __align__(16) unsigned short sBh[128 * PITCH];
    __shared__ __align__(16) unsigned short sBl[128 * PITCH];
    __shared__ float sred[2048];

    const int tid = threadIdx.x;
    const int lane = tid & 63;
    const int wid = tid >> 6;
    const int col15 = lane & 15;
    const int quad = lane >> 4;
    const int wm = (wid >> 1) * 64;
    const int wo = (wid & 1) * 64;
    const int m0 = blockIdx.x * 128;
    const int o0 = blockIdx.y * 128;
    const int YB = gridDim.x;
    const int lr = tid >> 2;
    const int lc = (tid & 3) * 8;

    f32x4 acc[4][4];
#pragma unroll
    for (int mt = 0; mt < 4; ++mt)
#pragma unroll
        for (int ot = 0; ot < 4; ++ot)
            acc[mt][ot] = {0.f, 0.f, 0.f, 0.f};

    for (int k0 = 0; k0 < CPW; k0 += 32) {
#pragma unroll
        for (int it = 0; it < 2; ++it) {
            int r = lr + it * 64;
            int c = k0 + lc;
            unsigned short h[8], l[8];
            if (c + 8 <= AC) {
                const float* xr = X + (size_t)(m0 + r) * AC + c;
                float4 v0 = *(const float4*)xr;
                float4 v1 = *(const float4*)(xr + 4);
                float vv[8] = {v0.x, v0.y, v0.z, v0.w, v1.x, v1.y, v1.z, v1.w};
#pragma unroll
                for (int j = 0; j < 8; ++j) {
                    float v = vv[j];
                    if (applyAct) v = fmaxf(v * scale[c + j] + shift[c + j], 0.f);
                    f2bf_split(v, h[j], l[j]);
                }
            } else {
#pragma unroll
                for (int j = 0; j < 8; ++j) { h[j] = 0; l[j] = 0; }
            }
            *(ushort4*)&sAh[r * PITCH + lc] = make_ushort4(h[0], h[1], h[2], h[3]);
            *(ushort4*)&sAh[r * PITCH + lc + 4] = make_ushort4(h[4], h[5], h[6], h[7]);
            *(ushort4*)&sAl[r * PITCH + lc] = make_ushort4(l[0], l[1], l[2], l[3]);
            *(ushort4*)&sAl[r * PITCH + lc + 4] = make_ushort4(l[4], l[5], l[6], l[7]);
        }
#pragma unroll
        for (int it = 0; it < 2; ++it) {
            int r = lr + it * 64;
            int c = k0 + lc;
            int o = o0 + r;
            uint4 vh = {0, 0, 0, 0}, vl = {0, 0, 0, 0};
            if (o < O && c < CPW) {
                size_t goff = (size_t)o * CPW + c;
                vh = *(const uint4*)(Bh + goff);
                vl = *(const uint4*)(Bl + goff);
            }
            *(uint4*)&sBh[r * PITCH + lc] = vh;
            *(uint4*)&sBl[r * PITCH + lc] = vl;
        }
        __syncthreads();
        s16x8 ah[4], al[4], bh[4], bl[4];
#pragma unroll
        for (int mt = 0; mt < 4; ++mt) {
            int rowoff = (wm + mt * 16 + col15) * PITCH + quad * 8;
            ah[mt] = *(const s16x8*)&sAh[rowoff];
            al[mt] = *(const s16x8*)&sAl[rowoff];
        }
#pragma unroll
        for (int ot = 0; ot < 4; ++ot) {
            int rowoff = (wo + ot * 16 + col15) * PITCH + quad * 8;
            bh[ot] = *(const s16x8*)&sBh[rowoff];
            bl[ot] = *(const s16x8*)&sBl[rowoff];
        }
#pragma unroll
        for (int mt = 0; mt < 4; ++mt)
#pragma unroll
            for (int ot = 0; ot < 4; ++ot) {
                acc[mt][ot] = __builtin_amdgcn_mfma_f32_16x16x32_bf16(
                    ah[mt], bl[ot], acc[mt][ot], 0, 0, 0);
                acc[mt][ot] = __builtin_amdgcn_mfma_f32_16x16x32_bf16(
                    al[mt], bh[ot], acc[mt][ot], 0, 0, 0);
                acc[mt][ot] = __builtin_amdgcn_mfma_f32_16x16x32_bf16(
                    ah[mt], bh[ot], acc[mt][ot], 0, 0, 0);
            }
        __syncthreads();
    }
#pragma unroll
    for (int mt = 0; mt < 4; ++mt)
#pragma unroll
        for (int ot = 0; ot < 4; ++ot) {
            int og = o0 + wo + ot * 16 + col15;
            if (og < O) {
#pragma unroll
                for (int r = 0; r < 4; ++r) {
                    int mg = m0 + wm + mt * 16 + quad * 4 + r;
                    Y[(size_t)mg * O + og] = acc[mt][ot][r];
                }
            }
        }
    // BN stats epilogue (deterministic fixed-order combine).
#pragma unroll
    for (int ot = 0; ot < 4; ++ot) {
        float s = 0.f, s2 = 0.f;
#pragma unroll
        for (int mt = 0; mt < 4; ++mt)
#pragma unroll
            for (int r = 0; r < 4; ++r) {
                float v = acc[mt][ot][r];
                s += v;
                s2 += v * v;
            }
        int slot = ((wid * 4 + quad) * 16 + col15) * 4 + ot;
        sred[slot * 2] = s;
        sred[slot * 2 + 1] = s2;
    }
    __syncthreads();
    if (tid < 128) {
        int col = tid;
        int o = o0 + col;
        if (o < O) {
            int cb = col >> 6;
            int ot = (col & 63) >> 4;
            int c15 = col & 15;
            double S = 0.0, S2 = 0.0;
#pragma unroll
            for (int wp = 0; wp < 2; ++wp) {
                int wd = cb + wp * 2;
#pragma unroll
                for (int q = 0; q < 4; ++q) {
                    int slot = ((wd * 4 + q) * 16 + c15) * 4 + ot;
                    S += (double)sred[slot * 2];
                    S2 += (double)sred[slot * 2 + 1];
                }
            }
            part[(size_t)o * YB + blockIdx.x] = S;
            part[(size_t)O * YB + (size_t)o * YB + blockIdx.x] = S2;
        }
    }
}

// ---------------- finalize BN: one block per channel (parallel, coalesced) --
__global__ __launch_bounds__(256) void finalize_bn(
    const double* __restrict__ part, const float* __restrict__ g,
    const float* __restrict__ bb, float* __restrict__ scale,
    float* __restrict__ shift, int O, int YB, double invM)
{
    int o = blockIdx.x;
    int tid = threadIdx.x;
    double s = 0.0, s2 = 0.0;
    for (int yb = tid; yb < YB; yb += 256) {
        s  += part[(size_t)o * YB + yb];
        s2 += part[(size_t)O * YB + (size_t)o * YB + yb];
    }
    __shared__ double sd[512];
    sd[tid] = s;
    sd[256 + tid] = s2;
    __syncthreads();
#pragma unroll
    for (int st = 128; st > 0; st >>= 1) {
        if (tid < st) {
            sd[tid] += sd[tid + st];
            sd[256 + tid] += sd[256 + tid + st];
        }
        __syncthreads();
    }
    if (tid == 0) {
        double mean = sd[0] * invM;
        double var = sd[256] * invM - mean * mean;
        float varf = (float)var;
        if (varf < 0.f) varf = 0.f;
        float sc = g[o] * rsqrtf(varf + 1e-5f);
        scale[o] = sc;
        shift[o] = bb[o] - (float)mean * sc;
    }
}

// ---------------- BN + ReLU + max over K ----------------
__global__ __launch_bounds__(256) void bn_relu_max(
    const float* __restrict__ Y, const float* __restrict__ scale,
    const float* __restrict__ shift, float* __restrict__ out,
    int Stot, int K, int O)
{
    int idx = blockIdx.x * 256 + threadIdx.x;
    if (idx >= Stot * O) return;
    int s = idx / O;
    int o = idx - s * O;
    const float* base = Y + (size_t)s * K * O + o;
    float sc = scale[o], sh = shift[o];
    float mx = 0.f;
    for (int k = 0; k < K; ++k) {
        float v = base[(size_t)k * O] * sc + sh;
        v = fmaxf(v, 0.f);
        mx = fmaxf(mx, v);
    }
    out[idx] = mx;
}

// ============================================================================
extern "C" void kernel_launch(void* const* d_in, const int* in_sizes, int n_in,
                              void* d_out, int out_size, void* d_ws, size_t ws_size,
                              hipStream_t stream)
{
    const float* xin = (const float*)d_in[0];
    const float* w[9]; const float* g[9]; const float* bb[9];
    for (int i = 0; i < 9; ++i) {
        w[i]  = (const float*)d_in[1 + 3 * i];
        g[i]  = (const float*)d_in[2 + 3 * i];
        bb[i] = (const float*)d_in[3 + 3 * i];
    }

    char* base = (char*)d_ws;
    size_t off = 0;
    auto alloc = [&](size_t bytes) -> void* {
        void* p = base + off;
        off = (off + bytes + 255) & ~(size_t)255;
        return p;
    };
    const int OC[9][3] = {{64,4,8},{64,64,64},{128,64,64},
                          {128,131,136},{128,128,128},{256,128,128},
                          {256,259,264},{512,256,256},{1024,512,512}};
    size_t woff[10]; woff[0] = 0;
    for (int i = 0; i < 9; ++i) woff[i + 1] = woff[i] + (size_t)OC[i][0] * OC[i][2];

    // --- small / metadata region (memset-protected) ---
    int*    fps1   = (int*)alloc((size_t)4096 * 4);
    int*    fps2   = (int*)alloc((size_t)1024 * 4);
    int*    qb2    = (int*)alloc((size_t)65536 * 4);
    float*  nx1    = (float*)alloc((size_t)12288 * 4);
    float*  nx2    = (float*)alloc((size_t)3072 * 4);
    float*  feat1  = (float*)alloc((size_t)524288 * 4);
    float*  feat2  = (float*)alloc((size_t)262144 * 4);
    double* part   = (double*)alloc((size_t)262144 * 8);
    float*  scales = (float*)alloc((size_t)9 * 1024 * 4);
    float*  shifts = (float*)alloc((size_t)9 * 1024 * 4);
    unsigned short* WH = (unsigned short*)alloc(woff[9] * 2);
    unsigned short* WL = (unsigned short*)alloc(woff[9] * 2);
    const size_t zeroBytes = off;
    // --- big ping/pong buffers: verified fully-written-before-read at every
    //     use (group*/gemm write the exact region the next consumer reads) ---
    float*  XG = (float*)alloc((size_t)65536 * 136 * 4);
    float*  A  = (float*)alloc((size_t)16777216 * 4);
    if (off > ws_size) return;

    // Defensive zero of the metadata region only (~5 MB): keeps every call
    // bit-identical regardless of harness ws poison for all index/stat paths.
    hipMemsetAsync(d_ws, 0, zeroBytes, stream);

    PWArgs pwa;
    for (int i = 0; i < 9; ++i) {
        pwa.w[i] = w[i]; pwa.off[i] = (unsigned)woff[i];
        pwa.O[i] = OC[i][0]; pwa.C[i] = OC[i][1]; pwa.CP[i] = OC[i][2];
    }
    prep_w_all<<<(int)((woff[9] + 255) / 256), 256, 0, stream>>>(pwa, WH, WL, (int)woff[9]);

    // ---------------- SA1 ----------------
    fps_block<256, 16, 4><<<8, 256, 0, stream>>>(xin, 512, fps1, nx1);
    qb_group1<<<(4096 * 64) / 256, 256, 0, stream>>>(xin, nx1, XG);

    // L1_0: (131072, AC=8) -> 64
    gemm_fused<<<dim3(1024, 1), 256, 0, stream>>>(XG, nullptr, nullptr, 0, WH + woff[0], WL + woff[0], A, part, 131072, 8, 8, 64);
    finalize_bn<<<64, 256, 0, stream>>>(part, g[0], bb[0], scales + 0 * 1024, shifts + 0 * 1024, 64, 1024, 1.0 / 131072.0);
    // L1_1: 64 -> 64
    gemm_fused<<<dim3(1024, 1), 256, 0, stream>>>(A, scales + 0 * 1024, shifts + 0 * 1024, 1, WH + woff[1], WL + woff[1], XG, part, 131072, 64, 64, 64);
    finalize_bn<<<64, 256, 0, stream>>>(part, g[1], bb[1], scales + 1 * 1024, shifts + 1 * 1024, 64, 1024, 1.0 / 131072.0);
    // L1_2: 64 -> 128
    gemm_fused<<<dim3(1024, 1), 256, 0, stream>>>(XG, scales + 1 * 1024, shifts + 1 * 1024, 1, WH + woff[2], WL + woff[2], A, part, 131072, 64, 64, 128);
    finalize_bn<<<128, 256, 0, stream>>>(part, g[2], bb[2], scales + 2 * 1024, shifts + 2 * 1024, 128, 1024, 1.0 / 131072.0);
    bn_relu_max<<<(4096 * 128) / 256, 256, 0, stream>>>(A, scales + 2 * 1024, shifts + 2 * 1024, feat1, 4096, 32, 128);

    // ---------------- SA2 ----------------
    fps_wave<8, 3><<<8, 64, 0, stream>>>(nx1, 128, fps2, nx2);
    query_ball_kernel<<<(8 * 128 * 64) / 256, 256, 0, stream>>>(
        nx1, 3, 512, nx2, 8 * 128, 128, 0.16f, 64, qb2);
    group2_kernel<<<(65536 * 136) / 256, 256, 0, stream>>>(nx1, feat1, qb2, nx2, XG);

    // L2_0: (65536, AC=136) -> 128
    gemm_fused<<<dim3(512, 1), 256, 0, stream>>>(XG, nullptr, nullptr, 0, WH + woff[3], WL + woff[3], A, part, 65536, 136, 136, 128);
    finalize_bn<<<128, 256, 0, stream>>>(part, g[3], bb[3], scales + 3 * 1024, shifts + 3 * 1024, 128, 512, 1.0 / 65536.0);
    // L2_1: 128 -> 128
    gemm_fused<<<dim3(512, 1), 256, 0, stream>>>(A, scales + 3 * 1024, shifts + 3 * 1024, 1, WH + woff[4], WL + woff[4], XG, part, 65536, 128, 128, 128);
    finalize_bn<<<128, 256, 0, stream>>>(part, g[4], bb[4], scales + 4 * 1024, shifts + 4 * 1024, 128, 512, 1.0 / 65536.0);
    // L2_2: 128 -> 256
    gemm_fused<<<dim3(512, 2), 256, 0, stream>>>(XG, scales + 4 * 1024, shifts + 4 * 1024, 1, WH + woff[5], WL + woff[5], A, part, 65536, 128, 128, 256);
    finalize_bn<<<256, 256, 0, stream>>>(part, g[5], bb[5], scales + 5 * 1024, shifts + 5 * 1024, 256, 512, 1.0 / 65536.0);
    bn_relu_max<<<(1024 * 256) / 256, 256, 0, stream>>>(A, scales + 5 * 1024, shifts + 5 * 1024, feat2, 1024, 64, 256);

    // ---------------- SA3 (group_all) ----------------
    group3_kernel<<<(1024 * 264) / 256, 256, 0, stream>>>(nx2, feat2, XG);

    // L3_0: (1024, AC=264) -> 256
    gemm_fused<<<dim3(8, 2), 256, 0, stream>>>(XG, nullptr, nullptr, 0, WH + woff[6], WL + woff[6], A, part, 1024, 264, 264, 256);
    finalize_bn<<<256, 256, 0, stream>>>(part, g[6], bb[6], scales + 6 * 1024, shifts + 6 * 1024, 256, 8, 1.0 / 1024.0);
    // L3_1: 256 -> 512
    gemm_fused<<<dim3(8, 4), 256, 0, stream>>>(A, scales + 6 * 1024, shifts + 6 * 1024, 1, WH + woff[7], WL + woff[7], XG, part, 1024, 256, 256, 512);
    finalize_bn<<<512, 256, 0, stream>>>(part, g[7], bb[7], scales + 7 * 1024, shifts + 7 * 1024, 512, 8, 1.0 / 1024.0);
    // L3_2: 512 -> 1024
    gemm_fused<<<dim3(8, 8), 256, 0, stream>>>(XG, scales + 7 * 1024, shifts + 7 * 1024, 1, WH + woff[8], WL + woff[8], A, part, 1024, 512, 512, 1024);
    finalize_bn<<<1024, 256, 0, stream>>>(part, g[8], bb[8], scales + 8 * 1024, shifts + 8 * 1024, 1024, 8, 1.0 / 1024.0);
    bn_relu_max<<<(8 * 1024) / 256, 256, 0, stream>>>(A, scales + 8 * 1024, shifts + 8 * 1024, (float*)d_out, 8, 128, 1024);
}